// Round 15
// baseline (77.046 us; speedup 1.0000x reference)
//
#include <hip/hip_runtime.h>
#include <hip/hip_bf16.h>
#include <stdint.h>

#define QMAX 127.0f

typedef __attribute__((ext_vector_type(4))) int   i32x4;
typedef __attribute__((ext_vector_type(2))) int   i32x2;
typedef __attribute__((ext_vector_type(4))) float f32x4v;

__device__ inline int quant_i(float x, float inv) {
    float q = rintf(x * inv);                 // inv = 127/absmax (one div per row)
    q = fminf(fmaxf(q, -QMAX), QMAX);
    return (int)q;                            // exact: q integral, |q|<=127
}

__device__ inline uint32_t pack4(f32x4v v, float inv) {
    return (uint32_t)(quant_i(v.x, inv) & 255)
         | ((uint32_t)(quant_i(v.y, inv) & 255) << 8)
         | ((uint32_t)(quant_i(v.z, inv) & 255) << 16)
         | ((uint32_t)(quant_i(v.w, inv) & 255) << 24);
}

__device__ inline float amax8(f32x4v a, f32x4v b) {
    return fmaxf(fmaxf(fmaxf(fabsf(a.x), fabsf(a.y)), fmaxf(fabsf(a.z), fabsf(a.w))),
                 fmaxf(fmaxf(fabsf(b.x), fabsf(b.y)), fmaxf(fabsf(b.z), fabsf(b.w))));
}

// ---- kernel 1: quantize rhs along axis 0 into FRAGMENT-MAJOR Btf ----
// offset(f,k) = (k>>6)*32768 + (f>>4)*1024 + ((k>>4)&3)*256 + (f&15)*16 + (k&15)
// so a GEMM wave's B-frag load is base + lane*16 (fully coalesced 1KB/instr).
__global__ void quant_rhs_kernel(const float* __restrict__ rhs,
                                 int8_t* __restrict__ Btf,
                                 float* __restrict__ rscale) {
    const int lane = threadIdx.x & 63;
    const int wave = threadIdx.x >> 6;
    const int f = blockIdx.x * 4 + wave;
    float v[8];
    float amax = 0.f;
#pragma unroll
    for (int i = 0; i < 8; ++i) {
        v[i] = rhs[(size_t)(lane + 64 * i) * 512 + f];
        amax = fmaxf(amax, fabsf(v[i]));
    }
#pragma unroll
    for (int m = 1; m <= 32; m <<= 1)
        amax = fmaxf(amax, __shfl_xor(amax, m, 64));
    const float inv = amax > 0.f ? QMAX / amax : 0.f;
    if (lane == 0) rscale[f] = amax > 0.f ? amax * (1.0f / QMAX) : 1.0f;
    const int laneHi = lane >> 4, lane15 = lane & 15;
    const int fbase = (f >> 4) * 1024 + (f & 15) * 16 + laneHi * 256 + lane15;
#pragma unroll
    for (int i = 0; i < 8; ++i)
        Btf[i * 32768 + fbase] = (int8_t)quant_i(v[i], inv);
}

// ---- kernel 2: FUSED quant(lhs)+GEMM, block = 64 rows x full N=512 ----
// Phase 1 (proven quant structure): each of 8 waves quantizes 8 rows -> i8
//   into XOR-swizzled LDS via ds_write (register path: swizzle legal, rule 21).
// ONE barrier.
// Phase 2 (R14's proven inner loop): wave w owns 64 rows x cols [w*64,w*64+64);
//   8 K-steps of mfma_i32_16x16x64_i8; A from LDS (2-way = free), B straight
//   from L2-resident frag-major Btf (coalesced 1KB register loads).
// 32KB LDS + __launch_bounds__(512,4) -> 4 blocks/CU = 32 waves/CU, 4
// independent barrier domains (R11: many small domains win).
// No Aq round-trip: session HBM = lhs 128MB + out 128MB.
__global__ __launch_bounds__(512, 4) void fused_kernel(const float* __restrict__ lhs,
                                                       const int8_t* __restrict__ Btf,
                                                       const float* __restrict__ rscale,
                                                       float* __restrict__ out) {
    __shared__ int8_t A[32768];   // [64 rows][512 k] i8, XOR-swizzled
    __shared__ float lsc[64];

    const int tid  = threadIdx.x;
    const int lane = tid & 63;
    const int wave = tid >> 6;          // 0..7
    const int m0   = blockIdx.x << 6;   // 64 rows per block

    // ---- phase 1: quantize rows m0..m0+63; wave w -> rows w*8..w*8+7 ----
    {
        const int r0 = wave * 8;
        const float* rp = lhs + (size_t)(m0 + r0) * 512 + lane * 8;
#pragma unroll
        for (int r = 0; r < 8; r += 2) {
            const f32x4v a0 = __builtin_nontemporal_load((const f32x4v*)(rp + (size_t)r * 512));
            const f32x4v b0 = __builtin_nontemporal_load((const f32x4v*)(rp + (size_t)r * 512 + 4));
            const f32x4v a1 = __builtin_nontemporal_load((const f32x4v*)(rp + (size_t)(r + 1) * 512));
            const f32x4v b1 = __builtin_nontemporal_load((const f32x4v*)(rp + (size_t)(r + 1) * 512 + 4));
            float q0 = amax8(a0, b0);
            float q1 = amax8(a1, b1);
#pragma unroll
            for (int m = 1; m <= 32; m <<= 1) {    // interleaved dual reduce
                q0 = fmaxf(q0, __shfl_xor(q0, m, 64));
                q1 = fmaxf(q1, __shfl_xor(q1, m, 64));
            }
            const float inv0 = q0 > 0.f ? QMAX / q0 : 0.f;
            const float inv1 = q1 > 0.f ? QMAX / q1 : 0.f;
            const int row0 = r0 + r, row1 = r0 + r + 1;
            if (lane == 0) {
                lsc[row0] = q0 > 0.f ? q0 * (1.0f / QMAX) : 1.0f;
                lsc[row1] = q1 > 0.f ? q1 * (1.0f / QMAX) : 1.0f;
            }
            i32x2 p0, p1;
            p0.x = (int)pack4(a0, inv0); p0.y = (int)pack4(b0, inv0);
            p1.x = (int)pack4(a1, inv1); p1.y = (int)pack4(b1, inv1);
            // swizzled LDS write (8B-aligned: XOR touches bits 4..6 only)
            *(i32x2*)(A + ((row0 * 512 + lane * 8) ^ ((row0 & 7) << 4))) = p0;
            *(i32x2*)(A + ((row1 * 512 + lane * 8) ^ ((row1 & 7) << 4))) = p1;
        }
    }
    __syncthreads();   // the only barrier: A + lsc complete

    // ---- phase 2: GEMM 64x512; wave w -> cols [w*64, w*64+64) ----
    const int lane15  = lane & 15;
    const int laneHi  = lane >> 4;
    const int colBase = wave * 64;
    const int8_t* bbase = Btf + (size_t)wave * 4096 + lane * 16;

    i32x4 acc[4][4];
#pragma unroll
    for (int i = 0; i < 4; ++i)
#pragma unroll
        for (int jj = 0; jj < 4; ++jj)
            acc[i][jj] = (i32x4){0, 0, 0, 0};

#pragma unroll
    for (int ks = 0; ks < 8; ++ks) {               // k = ks*64
        i32x4 bf[4], af[4];
#pragma unroll
        for (int ni = 0; ni < 4; ++ni)             // B: coalesced 1KB loads from L2
            bf[ni] = *(const i32x4*)(bbase + (size_t)ks * 32768 + ni * 1024);
#pragma unroll
        for (int mi = 0; mi < 4; ++mi) {           // A: swizzled LDS (2-way = free)
            const int row = mi * 16 + lane15;
            const int kb  = row * 512 + ks * 64 + laneHi * 16;
            af[mi] = *(const i32x4*)(A + (kb ^ ((row & 7) << 4)));
        }
#pragma unroll
        for (int mi = 0; mi < 4; ++mi)
#pragma unroll
            for (int ni = 0; ni < 4; ++ni)
                acc[mi][ni] = __builtin_amdgcn_mfma_i32_16x16x64_i8(
                    af[mi], bf[ni], acc[mi][ni], 0, 0, 0);
    }

    // ---- epilogue: C/D layout col=lane&15, row=(lane>>4)*4+reg ----
    float rs[4];
#pragma unroll
    for (int ni = 0; ni < 4; ++ni)
        rs[ni] = rscale[colBase + ni * 16 + lane15];
    const int rg = laneHi * 4;
#pragma unroll
    for (int mi = 0; mi < 4; ++mi) {
#pragma unroll
        for (int r = 0; r < 4; ++r) {
            const int lrow = mi * 16 + rg + r;
            const float ls = lsc[lrow];
            float* op = out + (size_t)(m0 + lrow) * 512 + colBase;
#pragma unroll
            for (int ni = 0; ni < 4; ++ni)
                op[ni * 16 + lane15] = (float)acc[mi][ni][r] * ls * rs[ni];
        }
    }
}

extern "C" void kernel_launch(void* const* d_in, const int* in_sizes, int n_in,
                              void* d_out, int out_size, void* d_ws, size_t ws_size,
                              hipStream_t stream) {
    const float* lhs = (const float*)d_in[0];   // [4,16384,512] f32
    const float* rhs = (const float*)d_in[1];   // [512,512] f32
    float* out = (float*)d_out;                 // [4,16384,512] f32

    // ws: Btf i8 frag-major (256KB) | rscale f32[512]
    char* ws = (char*)d_ws;
    int8_t* Btf   = (int8_t*)ws;
    float* rscale = (float*)(ws + 262144);

    const int rows = in_sizes[0] / 512;         // 65536

    quant_rhs_kernel<<<128, 256, 0, stream>>>(rhs, Btf, rscale);
    fused_kernel<<<rows / 64, 512, 0, stream>>>(lhs, Btf, rscale, out);
}